// Round 8
// baseline (21.703 us; speedup 1.0000x reference)
//
#include <hip/hip_runtime.h>
#include <math.h>

#define NB 6   // GRID_N + K basis functions

struct Params {
    float sb0[3], sp0[3];
    float b0;
    float sb1, sp1;
    float k3, k6, kh;   // ki0/3, ki0/6, ki0/2
    float cL;           // ki1 * 0.5 * ln2
    float ch;           // ki1 * 0.5
};

__device__ __forceinline__ float fexp2(float x) { return __builtin_amdgcn_exp2f(x); }
__device__ __forceinline__ float flog2(float x) { return __builtin_amdgcn_logf(x); }
__device__ __forceinline__ float frcp(float x)  { return __builtin_amdgcn_rcpf(x); }
__device__ __forceinline__ float frsq(float x)  { return __builtin_amdgcn_rsqf(x); }

// Per-cell folded cubic (validated r5/r7), single 16B fetch:
//   S  = a0 + f(a1 + f(a2 + f a3)) ;  S' = 1.5*(a1 + f(2 a2 + 3 a3 f))
__device__ __forceinline__ void spline_eval(float x, const float4* __restrict__ tab,
                                            float& sp, float& dsp) {
    float u  = fmaf(x, 1.5f, 4.5f);
    float fi = floorf(u);
    float f  = u - fi;
    int   i  = (int)fi;
    bool  in = (u >= 0.0f && u < 9.0f);
    float msk   = in ? 1.0f : 0.0f;
    float msk15 = in ? 1.5f : 0.0f;
    i = i < 0 ? 0 : (i > 8 ? 8 : i);
    const float4 A = tab[i];
    sp  = msk  * fmaf(fmaf(fmaf(A.w, f, A.z), f, A.y), f, A.x);
    float a2z = A.z + A.z;
    float f3  = 3.0f * f;
    dsp = msk15 * fmaf(f, fmaf(f3, A.w, a2z), A.y);
}

__device__ __forceinline__ void silu_fd(float x, float& s, float& ds) {
    float e   = fexp2(-1.44269504f * x);
    float sig = frcp(1.0f + e);
    s  = x * sig;
    ds = sig * fmaf(x, 1.0f - sig, 1.0f);
}

// Analytic gradient, half-coordinate log2-space form (validated r7).
__device__ void grad_sample(float s1, float s2, float s3, const Params& P,
                            const float4 (*__restrict__ tab)[9], float g[3]) {
    float q   = s1 - s2;
    float m   = s1 + s2 + 1.0f;
    float b   = s3;
    float h2  = fmaf(q, q, b * b);
    float irr = h2 > 0.0f ? frsq(h2) : 0.0f;   // 1/r (0 at h2<=0, JAX where)
    float r   = h2 * irr;
    float t1  = m - r, t2 = m + r;
    float invDet = frcp(t1 * t2);
    float invt1 = t2 * invDet, invt2 = t1 * invDet;
    float Lt1 = flog2(t1), Lt2 = flog2(t2);
    float x0  = fexp2(fmaf(Lt1, P.k3, -Lt2 * P.k6));
    float x1  = fexp2(fmaf(Lt2, P.k3, -Lt1 * P.k6));
    float x2  = (Lt1 + Lt2) * P.cL;

    float xs[3] = {x0, x1, x2};
    float hacc  = P.b0;
    float gx[3];
#pragma unroll
    for (int i = 0; i < 3; ++i) {
        float sp, dsp;
        spline_eval(xs[i], tab[i], sp, dsp);
        float si, dsi; silu_fd(xs[i], si, dsi);
        hacc += P.sb0[i] * si + P.sp0[i] * sp;
        gx[i] = P.sb0[i] * dsi + P.sp0[i] * dsp;
    }
    float sp2, dsp2;
    spline_eval(hacc, tab[3], sp2, dsp2);
    float si2, dsi2; silu_fd(hacc, si2, dsi2);
    float dWdh = P.sb1 * dsi2 + P.sp1 * dsp2;

    float P0 = dWdh * gx[0] * x0;
    float P1 = dWdh * gx[1] * x1;
    float w2c = dWdh * gx[2];
    float A = P.kh * P0 * invt1;
    float B = P.kh * P1 * invt2;
    float C = invDet * fmaf(-P.k6, P0 + P1, P.ch * w2c);
    float u0 = (B - A) * irr;
    float w  = fmaf(C, m, 0.5f * (A + B));
    float t  = q * fmaf(0.5f, u0, -C);
    g[0] = 2.0f * (w + t);
    g[1] = 2.0f * (w - t);
    g[2] = b * fmaf(-2.0f, C, u0);
}

#define CHUNK 1024           // samples per block-chunk
#define CHUNK_F4 768         // CHUNK*3/4 float4s

__global__ __launch_bounds__(256) void kan_grad(
        const float* __restrict__ strain, float* __restrict__ out, int n,
        const float* __restrict__ c0, const float* __restrict__ sb0,
        const float* __restrict__ sp0, const float* __restrict__ b0,
        const float* __restrict__ c1, const float* __restrict__ sb1,
        const float* __restrict__ sp1, const float* __restrict__ ki0,
        const float* __restrict__ ki1) {
    __shared__ float4 tab[4][9];
    __shared__ float g0s[3];
    __shared__ float buf[CHUNK * 3];   // 12 KB staging

    const int t = threadIdx.x;
    if (t < 36) {
        int tbl = t / 9, cell = t % 9;
        const float* cp = (tbl < 3) ? (c0 + tbl * NB) : c1;
        float cv[4];
#pragma unroll
        for (int kk = 0; kk < 4; ++kk) {
            int j = cell + kk - 3;
            cv[kk] = (j >= 0 && j < NB) ? cp[j] : 0.0f;
        }
        const float c16 = 1.0f / 6.0f;
        float a0 = (cv[0] + 4.0f * cv[1] + cv[2]) * c16;
        float a1 = (cv[2] - cv[0]) * 0.5f;
        float a2 = (cv[0] - 2.0f * cv[1] + cv[2]) * 0.5f;
        float a3 = (cv[3] - cv[0] + 3.0f * (cv[1] - cv[2])) * c16;
        tab[tbl][cell] = make_float4(a0, a1, a2, a3);
    }

    Params P;
#pragma unroll
    for (int i = 0; i < 3; ++i) { P.sb0[i] = sb0[i]; P.sp0[i] = sp0[i]; }
    P.b0 = b0[0];
    P.sb1 = sb1[0]; P.sp1 = sp1[0];
    float k = ki0[0], l = ki1[0];
    P.k3 = k * (1.0f / 3.0f);
    P.k6 = k * (1.0f / 6.0f);
    P.kh = k * 0.5f;
    P.cL = l * 0.34657359f;
    P.ch = l * 0.5f;

    __syncthreads();
    if (t == 0) {
        float g0[3];
        grad_sample(0.0f, 0.0f, 0.0f, P, tab, g0);
        g0s[0] = g0[0]; g0s[1] = g0[1]; g0s[2] = g0[2];
    }
    __syncthreads();
    const float g00 = g0s[0], g01 = g0s[1], g02 = g0s[2];

    const int nchunks = (n + CHUNK - 1) / CHUNK;
    for (int ch = blockIdx.x; ch < nchunks; ch += gridDim.x) {
        size_t s0 = (size_t)ch * CHUNK;
        int cnt = n - (int)s0; if (cnt > CHUNK) cnt = CHUNK;
        if (cnt == CHUNK) {
            // ---- stage in: perfectly coalesced ----
            const float4* g4 = reinterpret_cast<const float4*>(strain + s0 * 3);
            float4* b4 = reinterpret_cast<float4*>(buf);
            b4[t]       = g4[t];
            b4[t + 256] = g4[t + 256];
            b4[t + 512] = g4[t + 512];
            __syncthreads();
            // ---- compute 4 samples from private LDS slice (16B-aligned) ----
            float4* mine = reinterpret_cast<float4*>(buf + t * 12);
            float4 i0v = mine[0], i1v = mine[1], i2v = mine[2];
            float in[12] = { i0v.x, i0v.y, i0v.z, i0v.w,
                             i1v.x, i1v.y, i1v.z, i1v.w,
                             i2v.x, i2v.y, i2v.z, i2v.w };
            float o[12];
#pragma unroll
            for (int kk = 0; kk < 4; ++kk) {
                float g[3];
                grad_sample(in[3 * kk], in[3 * kk + 1], in[3 * kk + 2], P, tab, g);
                o[3 * kk]     = g[0] - g00;
                o[3 * kk + 1] = g[1] - g01;
                o[3 * kk + 2] = g[2] - g02;
            }
            mine[0] = make_float4(o[0], o[1], o[2],  o[3]);
            mine[1] = make_float4(o[4], o[5], o[6],  o[7]);
            mine[2] = make_float4(o[8], o[9], o[10], o[11]);
            __syncthreads();
            // ---- stage out: perfectly coalesced ----
            float4* o4 = reinterpret_cast<float4*>(out + s0 * 3);
            o4[t]       = b4[t];
            o4[t + 256] = b4[t + 256];
            o4[t + 512] = b4[t + 512];
            __syncthreads();   // buf reused next iteration
        } else {
            for (int i = (int)s0 + t; i < n; i += 256) {
                float g[3];
                grad_sample(strain[3 * i], strain[3 * i + 1], strain[3 * i + 2], P,
                            tab, g);
                out[3 * i]     = g[0] - g00;
                out[3 * i + 1] = g[1] - g01;
                out[3 * i + 2] = g[2] - g02;
            }
            __syncthreads();
        }
    }
}

extern "C" void kernel_launch(void* const* d_in, const int* in_sizes, int n_in,
                              void* d_out, int out_size, void* d_ws, size_t ws_size,
                              hipStream_t stream) {
    const float* strain = (const float*)d_in[0];
    const float* c0  = (const float*)d_in[1];
    const float* sb0 = (const float*)d_in[2];
    const float* sp0 = (const float*)d_in[3];
    const float* b0  = (const float*)d_in[4];
    const float* c1  = (const float*)d_in[5];
    const float* sb1 = (const float*)d_in[6];
    const float* sp1 = (const float*)d_in[7];
    // d_in[8] = b1: no effect on gradient
    const float* ki0 = (const float*)d_in[9];
    const float* ki1 = (const float*)d_in[10];

    int n = in_sizes[0] / 3;                 // number of samples
    int nchunks = (n + CHUNK - 1) / CHUNK;
    int grid = nchunks < 8192 ? nchunks : 8192;

    kan_grad<<<grid, 256, 0, stream>>>(strain, (float*)d_out, n,
                                       c0, sb0, sp0, b0, c1, sb1, sp1, ki0, ki1);
}

// Round 9
// 19.160 us; speedup vs baseline: 1.1327x; 1.1327x over previous
//
#include <hip/hip_runtime.h>
#include <math.h>

#define NB 6   // GRID_N + K basis functions

struct Params {
    float sb0_0, sb0_1, sb0_2;
    float b0, sb1;
    float k3, k6, kh;   // ki0/3, ki0/6, ki0/2
    float cL;           // ki1 * 0.5 * ln2
    float ch;           // ki1 * 0.5
};

__device__ __forceinline__ float fexp2(float x) { return __builtin_amdgcn_exp2f(x); }
__device__ __forceinline__ float flog2(float x) { return __builtin_amdgcn_logf(x); }
__device__ __forceinline__ float frcp(float x)  { return __builtin_amdgcn_rcpf(x); }
__device__ __forceinline__ float frsq(float x)  { return __builtin_amdgcn_rsqf(x); }

// Zero-padded 12-cell per-spline table (cells 0,10,11 = all-zero pads), rows
// pre-scaled by sp. Cell layout: u = (x+3)/h + 1, real cells 1..9.
// A = {a0,a1,a2,a3} value coeffs; B = {1.5a1, 3a2, 4.5a3, 0} deriv coeffs.
// Out-of-grid x lands in a zero cell -> sp=dsp=0 (matches reference mask).
__device__ __forceinline__ void spline_sd(float x, const float4* __restrict__ t4,
                                          float& sp, float& dsp) {
    float u = fmaf(x, 1.5f, 5.5f);
    int   i = (int)u;                       // trunc == floor for u>=0; u<0 clamps to pad
    i = i < 0 ? 0 : (i > 11 ? 11 : i);
    float f = u - (float)i;
    float4 A = t4[2 * i];
    float4 B = t4[2 * i + 1];
    sp  = fmaf(fmaf(fmaf(A.w, f, A.z), f, A.y), f, A.x);
    dsp = fmaf(fmaf(B.z, f, B.y), f, B.x);
}

__device__ __forceinline__ float spline_d(float x, const float4* __restrict__ t4) {
    float u = fmaf(x, 1.5f, 5.5f);
    int   i = (int)u;
    i = i < 0 ? 0 : (i > 11 ? 11 : i);
    float f = u - (float)i;
    float4 B = t4[2 * i + 1];
    return fmaf(fmaf(B.z, f, B.y), f, B.x);
}

__device__ __forceinline__ void silu_fd(float x, float& s, float& ds) {
    float sig = frcp(1.0f + fexp2(-1.44269504f * x));
    s  = x * sig;
    ds = sig * fmaf(x, 1.0f - sig, 1.0f);
}

__device__ __forceinline__ float silu_d(float x) {
    float sig = frcp(1.0f + fexp2(-1.44269504f * x));
    return sig * fmaf(x, 1.0f - sig, 1.0f);
}

// Analytic gradient, half-coordinate log2-space form (validated r7);
// layer-2 evaluates derivatives only (W value is never needed).
__device__ __forceinline__ void grad_sample(float s1, float s2, float s3,
        const Params& P, const float4* __restrict__ tb, float g[3]) {
    float q   = s1 - s2;
    float m   = s1 + s2 + 1.0f;
    float b   = s3;
    float h2  = fmaf(q, q, b * b);
    float irr = h2 > 0.0f ? frsq(h2) : 0.0f;   // 1/r (0 at h2<=0, JAX where)
    float r   = h2 * irr;
    float t1  = m - r, t2 = m + r;
    float invDet = frcp(t1 * t2);
    float invt1 = t2 * invDet, invt2 = t1 * invDet;
    float Lt1 = flog2(t1), Lt2 = flog2(t2);
    float x0  = fexp2(fmaf(Lt1, P.k3, -Lt2 * P.k6));
    float x1  = fexp2(fmaf(Lt2, P.k3, -Lt1 * P.k6));
    float x2  = (Lt1 + Lt2) * P.cL;

    float S0, D0, S1v, D1, S2v, D2;
    spline_sd(x0, tb,      S0,  D0);
    spline_sd(x1, tb + 24, S1v, D1);
    spline_sd(x2, tb + 48, S2v, D2);
    float si0, dsi0, si1, dsi1, si2, dsi2;
    silu_fd(x0, si0, dsi0);
    silu_fd(x1, si1, dsi1);
    silu_fd(x2, si2, dsi2);
    float hacc = P.b0 + fmaf(P.sb0_0, si0, S0) + fmaf(P.sb0_1, si1, S1v)
               + fmaf(P.sb0_2, si2, S2v);
    float gx0 = fmaf(P.sb0_0, dsi0, D0);
    float gx1 = fmaf(P.sb0_1, dsi1, D1);
    float gx2 = fmaf(P.sb0_2, dsi2, D2);

    float dWdh = fmaf(P.sb1, silu_d(hacc), spline_d(hacc, tb + 72));

    float P0  = dWdh * gx0 * x0;
    float P1  = dWdh * gx1 * x1;
    float w2c = dWdh * gx2;
    float A = P.kh * P0 * invt1;
    float B = P.kh * P1 * invt2;
    float C = invDet * fmaf(-P.k6, P0 + P1, P.ch * w2c);
    float u0 = (B - A) * irr;
    float w  = fmaf(C, m, 0.5f * (A + B));
    float t  = q * fmaf(0.5f, u0, -C);
    g[0] = 2.0f * (w + t);
    g[1] = 2.0f * (w - t);
    g[2] = b * fmaf(-2.0f, C, u0);
}

__global__ __launch_bounds__(256) void kan_grad(
        const float* __restrict__ strain, float* __restrict__ out, int n,
        const float* __restrict__ c0, const float* __restrict__ sb0,
        const float* __restrict__ sp0, const float* __restrict__ b0,
        const float* __restrict__ c1, const float* __restrict__ sb1,
        const float* __restrict__ sp1, const float* __restrict__ ki0,
        const float* __restrict__ ki1) {
    __shared__ float4 tab4[96];   // 4 tables x 12 cells x {A,B}

    const int t = threadIdx.x;

    Params P;
    P.sb0_0 = sb0[0]; P.sb0_1 = sb0[1]; P.sb0_2 = sb0[2];
    P.b0 = b0[0]; P.sb1 = sb1[0];
    float k = ki0[0], l = ki1[0];
    P.k3 = k * (1.0f / 3.0f);
    P.k6 = k * (1.0f / 6.0f);
    P.kh = k * 0.5f;
    P.cL = l * 0.34657359f;
    P.ch = l * 0.5f;

    if (t < 48) {
        int tbl = t / 12, cell = t % 12;
        float scale = (tbl < 3) ? sp0[tbl] : sp1[0];
        const float* cp = (tbl < 3) ? (c0 + tbl * NB) : c1;
        int  c    = cell - 1;                  // real cell index 0..8
        bool real = (cell >= 1 && cell <= 9);
        float cv[4];
#pragma unroll
        for (int kk = 0; kk < 4; ++kk) {
            int j = c + kk - 3;
            cv[kk] = (real && j >= 0 && j < NB) ? cp[j] : 0.0f;
        }
        const float c16 = 1.0f / 6.0f;
        float a0 = (cv[0] + 4.0f * cv[1] + cv[2]) * c16 * scale;
        float a1 = (cv[2] - cv[0]) * 0.5f * scale;
        float a2 = (cv[0] - 2.0f * cv[1] + cv[2]) * 0.5f * scale;
        float a3 = (cv[3] - cv[0] + 3.0f * (cv[1] - cv[2])) * c16 * scale;
        tab4[2 * t]     = make_float4(a0, a1, a2, a3);
        tab4[2 * t + 1] = make_float4(1.5f * a1, 3.0f * a2, 4.5f * a3, 0.0f);
    }
    __syncthreads();

    // ---- per-thread analytic g0 at s=0 (x0=x1=1 -> cell 7 f=0; x2=0 -> cell 5
    // f=0.5; irr=0 -> t-term and g2 vanish; silu(1),silu'(1),silu'(0) constant).
    const float SI1 = 0.73105858f, DSI1 = 0.92767051f;
    float S0g = tab4[2 * 7].x,        D0g = tab4[2 * 7 + 1].x;
    float S1g = tab4[2 * 19].x,       D1g = tab4[2 * 19 + 1].x;
    float4 A2 = tab4[2 * 29],         B2  = tab4[2 * 29 + 1];
    const float fh = 0.5f;
    float S2g = fmaf(fmaf(fmaf(A2.w, fh, A2.z), fh, A2.y), fh, A2.x);
    float D2g = fmaf(fmaf(B2.z, fh, B2.y), fh, B2.x);
    float hacc0 = P.b0 + fmaf(P.sb0_0, SI1, S0g) + fmaf(P.sb0_1, SI1, S1g) + S2g;
    float gx0g = fmaf(P.sb0_0, DSI1, D0g);
    float gx1g = fmaf(P.sb0_1, DSI1, D1g);
    float gx2g = fmaf(P.sb0_2, 0.5f, D2g);
    float dW0 = fmaf(P.sb1, silu_d(hacc0), spline_d(hacc0, tab4 + 72));
    float P0g = dW0 * gx0g, P1g = dW0 * gx1g, w2g = dW0 * gx2g;
    float Ag = P.kh * P0g, Bg = P.kh * P1g;
    float Cg = fmaf(-P.k6, P0g + P1g, P.ch * w2g);
    const float G = (Ag + Bg) + 2.0f * Cg;     // g0 = (G, G, 0)

    const int ngroups = (n + 3) >> 2;  // 4 samples (= 3 float4) per thread-task
    for (int gi = blockIdx.x * blockDim.x + t; gi < ngroups;
         gi += gridDim.x * blockDim.x) {
        int i0 = gi * 4;
        if (i0 + 4 <= n) {
            const float4* sp4 = reinterpret_cast<const float4*>(strain + (size_t)i0 * 3);
            float4 v0 = sp4[0], v1 = sp4[1], v2 = sp4[2];
            float in[12] = { v0.x, v0.y, v0.z, v0.w,
                             v1.x, v1.y, v1.z, v1.w,
                             v2.x, v2.y, v2.z, v2.w };
            float o[12];
#pragma unroll
            for (int kk = 0; kk < 4; ++kk) {
                float g[3];
                grad_sample(in[3 * kk], in[3 * kk + 1], in[3 * kk + 2], P, tab4, g);
                o[3 * kk]     = g[0] - G;
                o[3 * kk + 1] = g[1] - G;
                o[3 * kk + 2] = g[2];
            }
            float4* op4 = reinterpret_cast<float4*>(out + (size_t)i0 * 3);
            op4[0] = make_float4(o[0], o[1], o[2],  o[3]);
            op4[1] = make_float4(o[4], o[5], o[6],  o[7]);
            op4[2] = make_float4(o[8], o[9], o[10], o[11]);
        } else {
            for (int i = i0; i < n; ++i) {
                float g[3];
                grad_sample(strain[3 * i], strain[3 * i + 1], strain[3 * i + 2], P,
                            tab4, g);
                out[3 * i]     = g[0] - G;
                out[3 * i + 1] = g[1] - G;
                out[3 * i + 2] = g[2];
            }
        }
    }
}

extern "C" void kernel_launch(void* const* d_in, const int* in_sizes, int n_in,
                              void* d_out, int out_size, void* d_ws, size_t ws_size,
                              hipStream_t stream) {
    const float* strain = (const float*)d_in[0];
    const float* c0  = (const float*)d_in[1];
    const float* sb0 = (const float*)d_in[2];
    const float* sp0 = (const float*)d_in[3];
    const float* b0  = (const float*)d_in[4];
    const float* c1  = (const float*)d_in[5];
    const float* sb1 = (const float*)d_in[6];
    const float* sp1 = (const float*)d_in[7];
    // d_in[8] = b1: no effect on gradient
    const float* ki0 = (const float*)d_in[9];
    const float* ki1 = (const float*)d_in[10];

    int n = in_sizes[0] / 3;                 // number of samples
    int ngroups = (n + 3) / 4;
    int block = 256;
    int grid = (ngroups + block - 1) / block;
    if (grid > 8192) grid = 8192;

    kan_grad<<<grid, block, 0, stream>>>(strain, (float*)d_out, n,
                                         c0, sb0, sp0, b0, c1, sb1, sp1, ki0, ki1);
}